// Round 4
// baseline (253.181 us; speedup 1.0000x reference)
//
#include <hip/hip_runtime.h>
#include <hip/hip_bf16.h>
#include <stdint.h>

#define S_LEN 2048
#define HDIM  2048
#define NHQ   16
#define NKVH  4
#define HD    128
#define WIN   1024
#define SM_SCALE 0.08838834764831845f
#define NEG_BIG  -1.0e30f

typedef __attribute__((ext_vector_type(8))) short short8;
typedef __attribute__((ext_vector_type(4))) float float4v;
typedef unsigned short u16;

static __device__ __forceinline__ float bf2f(u16 u) {
  union { unsigned int i; float f; } v; v.i = ((unsigned int)u) << 16; return v.f;
}
static __device__ __forceinline__ u16 f2bf(float f) {
  union { float f; unsigned int i; } v; v.f = f;
  unsigned int x = v.i;
  return (u16)((x + 0x7fffu + ((x >> 16) & 1u)) >> 16);   // RNE, finite inputs
}

// ---------------------------------------------------------------------------
// prep: one kernel for all input conditioning.
//  blocks [0,1024):        hs fp32 -> packed-A bf16 (8KB tiles [kc][m 128][8])
//  blocks [1024,7168):     Wq|Wk|Wv -> packed-B WqkvT (4KB tiles [kc][n 64][8])
//  blocks [7168,11264):    Wo -> packed-B WoT
// ---------------------------------------------------------------------------
__global__ __launch_bounds__(256) void prep(
    const float* __restrict__ hs, const float* __restrict__ Wq,
    const float* __restrict__ Wk, const float* __restrict__ Wv,
    const float* __restrict__ Wo, u16* __restrict__ hsB,
    u16* __restrict__ WqkvT, u16* __restrict__ WoT)
{
  const int b = blockIdx.x;
  if (b < 1024) {
    // ---- hs pack ----
    u16* dst = hsB + (size_t)b * 4096;
    const int mb = b >> 6, ks = b & 63;
#pragma unroll
    for (int i = 0; i < 2; ++i) {
      const int cid = i * 256 + threadIdx.x;
      const int kc  = cid & 3;
      const int m   = cid >> 2;
      const float* src = hs + ((size_t)(mb * 128 + m)) * 2048 + ks * 32 + kc * 8;
      const float4 v0 = *(const float4*)src;
      const float4 v1 = *(const float4*)(src + 4);
      short8 o;
      o[0] = (short)f2bf(v0.x); o[1] = (short)f2bf(v0.y);
      o[2] = (short)f2bf(v0.z); o[3] = (short)f2bf(v0.w);
      o[4] = (short)f2bf(v1.x); o[5] = (short)f2bf(v1.y);
      o[6] = (short)f2bf(v1.z); o[7] = (short)f2bf(v1.w);
      *(short8*)(dst + (kc * 128 + m) * 8) = o;
    }
    return;
  }

  // ---- weight transpose -> packed B ----
  __shared__ u16 t[32][33];
  const int tx = threadIdx.x & 31, ty = threadIdx.x >> 5;
  int n0, kstep;
  const float* W; u16* DT; int nsrc, N;
  if (b < 7168) {
    const int bb = b - 1024;            // 96 n-tiles x 64 k-tiles
    n0    = (bb % 96) * 32;
    kstep = bb / 96;
    if (n0 < 2048)      { W = Wq; nsrc = n0;        N = 2048; }
    else if (n0 < 2560) { W = Wk; nsrc = n0 - 2048; N = 512;  }
    else                { W = Wv; nsrc = n0 - 2560; N = 512;  }
    DT = WqkvT;
  } else {
    const int bb = b - 7168;            // 64 x 64
    n0    = (bb & 63) * 32;
    kstep = bb >> 6;
    W = Wo; nsrc = n0; N = 2048; DT = WoT;
  }
  const int k0 = kstep * 32;

#pragma unroll
  for (int i = 0; i < 4; ++i)
    t[ty + i * 8][tx] = f2bf(W[(size_t)(k0 + ty + i * 8) * N + nsrc + tx]);
  __syncthreads();
  const int kc = tx >> 3, e = tx & 7;
#pragma unroll
  for (int i = 0; i < 4; ++i) {
    const int n = n0 + ty + i * 8;
    DT[((size_t)((n >> 6) * 64 + kstep)) * 2048 + kc * 512 + (n & 63) * 8 + e]
        = t[tx][ty + i * 8];
  }
}

// ---------------------------------------------------------------------------
// GEMM on packed operands: C = A*B^T, bf16 in, fp32 accum. 128x64 tile,
// 4 waves of 64x32, conflict-free k-major LDS. Double-buffered staging
// (BK=64), stage(t+1) issued before compute(t), one barrier per K-step.
// EPI=0: fp32 row-major out (out-projection, writes d_out).
// EPI=1: fused QKV epilogue — in-register RoPE (q,k), route q->Qb, k->Kp, v->Vp.
//        Kp/Vp are stored in MFMA-FRAGMENT ORDER so the attention kernel's
//        direct-L2 reads are fully coalesced (1KB contiguous per instruction):
//        Kp tile: panel (ks 4, nt 4) x [lane 64][e 8]; value K[key][d] at
//                 panel=ks*4+(key>>4), lane=((d>>3)&3)*16+(key&15), e=d&7
//        Vp tile: panel (ktk 2, nt2 8) x [lane 64][e 8]; value V[key][hd] at
//                 panel=ktk*8+(hd>>4),  lane=((key>>3)&3)*16+(hd&15), e=key&7
// ---------------------------------------------------------------------------
template <int EPI>
__global__ __launch_bounds__(256) void gemm_bt(
    const u16* __restrict__ Apk, const u16* __restrict__ Bpk,
    void* __restrict__ Cv, const float* __restrict__ fc,
    u16* __restrict__ Qb, u16* __restrict__ Kp, u16* __restrict__ Vp,
    int M, int N, int K)
{
  __shared__ u16 Als[2][8192];   // 32 KB
  __shared__ u16 Bls[2][4096];   // 16 KB

  const int tid  = threadIdx.x;
  const int lane = tid & 63;
  const int w    = tid >> 6;
  const int quad = lane >> 4;
  const int lc   = lane & 15;
  const int n0   = blockIdx.x * 64;
  const int m0   = blockIdx.y * 128;
  const int wr   = (w >> 1) * 64;
  const int wc   = (w & 1) * 32;
  const int ktiles = K >> 5;        // packed 32-k tiles
  const int nk2    = ktiles >> 1;   // 64-k double steps

  const char* aB = (const char*)(Apk + (size_t)(m0 >> 7) * ktiles * 4096);
  const char* bB = (const char*)(Bpk + (size_t)(n0 >> 6) * ktiles * 2048);

  float4v acc[4][2];
#pragma unroll
  for (int i = 0; i < 4; ++i)
#pragma unroll
    for (int j = 0; j < 2; ++j) acc[i][j] = (float4v){0.f, 0.f, 0.f, 0.f};

  auto stage = [&](int bi, int kk) {
    const char* ab = aB + (size_t)kk * 16384;
    const char* bb = bB + (size_t)kk * 8192;
#pragma unroll
    for (int r = 0; r < 4; ++r) {
      const int off = r * 4096 + tid * 16;
      __builtin_amdgcn_global_load_lds(
          (__attribute__((address_space(1))) void*)(ab + off),
          (__attribute__((address_space(3))) void*)((char*)Als[bi] + off), 16, 0, 0);
    }
#pragma unroll
    for (int r = 0; r < 2; ++r) {
      const int off = r * 4096 + tid * 16;
      __builtin_amdgcn_global_load_lds(
          (__attribute__((address_space(1))) void*)(bb + off),
          (__attribute__((address_space(3))) void*)((char*)Bls[bi] + off), 16, 0, 0);
    }
  };

  stage(0, 0);
  __syncthreads();                 // drains vmcnt: buf0 ready
  int cur = 0;
  for (int kk = 0; kk < nk2; ++kk) {
    if (kk + 1 < nk2) stage(cur ^ 1, kk + 1);   // in flight across compute
#pragma unroll
    for (int half = 0; half < 2; ++half) {
      const u16* Ab = Als[cur] + half * 4096;
      const u16* Bb = Bls[cur] + half * 2048;
      short8 af[4], bfr[2];
#pragma unroll
      for (int mi = 0; mi < 4; ++mi)
        af[mi] = *(const short8*)(Ab + quad * 1024 + (wr + mi * 16 + lc) * 8);
#pragma unroll
      for (int ni = 0; ni < 2; ++ni)
        bfr[ni] = *(const short8*)(Bb + quad * 512 + (wc + ni * 16 + lc) * 8);
#pragma unroll
      for (int mi = 0; mi < 4; ++mi)
#pragma unroll
        for (int ni = 0; ni < 2; ++ni)
          acc[mi][ni] = __builtin_amdgcn_mfma_f32_16x16x32_bf16(
              af[mi], bfr[ni], acc[mi][ni], 0, 0, 0);
    }
    __syncthreads();               // next buf ready + cur free for restage
    cur ^= 1;
  }

  if (EPI == 0) {
#pragma unroll
    for (int mi = 0; mi < 4; ++mi)
#pragma unroll
      for (int ni = 0; ni < 2; ++ni)
#pragma unroll
        for (int r = 0; r < 4; ++r) {
          const int row = m0 + wr + mi * 16 + quad * 4 + r;
          const int col = n0 + wc + ni * 16 + lc;
          ((float*)Cv)[(size_t)row * N + col] = acc[mi][ni][r];
        }
  } else {
    // ---- fused QKV epilogue: rope (q,k) + pack routing (block-uniform) ----
    if (n0 < 2560) {
#pragma unroll
      for (int mi = 0; mi < 4; ++mi)
#pragma unroll
        for (int ni = 0; ni < 2; ++ni)
#pragma unroll
          for (int r = 0; r < 4; ++r) {
            const int row = m0 + wr + mi * 16 + quad * 4 + r;
            const int col = n0 + wc + ni * 16 + lc;
            const int hh  = col & 127;                 // dim within head
            const float v = acc[mi][ni][r];
            const float p = __shfl_xor(v, 1);
            const float2 cs = *(const float2*)(fc + row * 128 + (hh & ~1));
            const float res = (col & 1) ? (p * cs.y + v * cs.x)
                                        : (v * cs.x - p * cs.y);
            if (n0 < 2048) {
              Qb[(size_t)row * 2048 + col] = f2bf(res);
            } else {
              // K -> fragment-order pack
              const int kvh = (col - 2048) >> 7;
              const int kt  = row >> 6, key = row & 63;
              const int ks   = hh >> 5;
              const int qd   = (hh >> 3) & 3;
              const int e    = hh & 7;
              const int ntk  = key >> 4;
              const int lck  = key & 15;
              Kp[((size_t)(kvh * 32 + kt)) * 8192
                 + ((ks * 4 + ntk) << 9) + ((qd * 16 + lck) << 3) + e] = f2bf(res);
            }
          }
    } else {
      // v section: fragment-order pack (V^T fragments)
#pragma unroll
      for (int mi = 0; mi < 4; ++mi)
#pragma unroll
        for (int ni = 0; ni < 2; ++ni)
#pragma unroll
          for (int r = 0; r < 4; ++r) {
            const int row = m0 + wr + mi * 16 + quad * 4 + r;
            const int col = n0 + wc + ni * 16 + lc;
            const int kvh = (col - 2560) >> 7;
            const int hd  = col & 127;
            const int kt  = row >> 6, key = row & 63;
            const int ktk  = (key >> 5) & 1;
            const int qd   = (key >> 3) & 3;
            const int e    = key & 7;
            const int nt2  = hd >> 4;
            const int lcv  = hd & 15;
            Vp[((size_t)(kvh * 32 + kt)) * 8192
               + ((ktk * 8 + nt2) << 9) + ((qd * 16 + lcv) << 3) + e]
                = f2bf(acc[mi][ni][r]);
          }
    }
  }
}

// ---------------------------------------------------------------------------
// Flash attention v6 — decoupled 1-wave blocks + fragment-order K/V:
//  * 2048 blocks x 64 threads: (t 32, h 16, w 4). ZERO barriers.
//  * K and V read DIRECTLY from L2-resident Kp/Vp which are stored in exact
//    MFMA-fragment order: every load is base + panel*1KB + lane*16B — a
//    single fully-coalesced contiguous 1KB transaction (v5's XOR-swizzled
//    layout made each load a 32-cache-line gather = TA throughput cap).
//  * LDS = 2.25 KB (P only); masked rows self-heal via alpha=exp(NEG_BIG)=0.
// ---------------------------------------------------------------------------
__global__ __launch_bounds__(64, 3) void attn_kernel(
    const u16* __restrict__ Qb, const u16* __restrict__ kp,
    const u16* __restrict__ vp, u16* __restrict__ out)
{
  __shared__ u16 P[16 * 72];       // per-wave P tile, 2.25 KB

  const int lane = threadIdx.x;    // 0..63
  const int quad = lane >> 4;
  const int lc   = lane & 15;

  const int id = blockIdx.x;
  const int u  = id & 255;
  const int g  = id >> 8;          // 0..7
  const int h  = u & 15;
  const int w  = (u >> 4) & 3;
  const int j2 = u >> 6;           // 0..3
  const int t  = g * 4 + j2;       // 0..31 (bijective over (g,j2))
  const int kvh = h >> 2;
  const int rb  = t * 64 + w * 16; // first q-row of this wave

  short8 qf[4];
  {
    const u16* qp = Qb + (size_t)(rb + lc) * 2048 + h * HD + quad * 8;
#pragma unroll
    for (int ks = 0; ks < 4; ++ks) qf[ks] = *(const short8*)(qp + ks * 32);
  }

  float4v o[8];
#pragma unroll
  for (int i = 0; i < 8; ++i) o[i] = (float4v){0.f, 0.f, 0.f, 0.f};
  float mrow[4], lrow[4];
#pragma unroll
  for (int r = 0; r < 4; ++r) { mrow[r] = NEG_BIG; lrow[r] = 0.f; }

  int jmin = rb - (WIN - 1); if (jmin < 0) jmin = 0;
  const int kt_begin = jmin >> 6;
  const int kt_end   = (rb + 15) >> 6;

  const size_t tbase = (size_t)(kvh * 32) * 8192;
  const int lofs = lane << 3;      // lane*8 elements = lane*16B

  for (int kt = kt_begin; kt <= kt_end; ++kt) {
    const int k0 = kt * 64;
    const u16* kg = kp + tbase + (size_t)kt * 8192;
    const u16* vg = vp + tbase + (size_t)kt * 8192;

    // ---- QK^T: K fragments straight from L2, coalesced 1KB loads ----
    float4v sacc[4];
#pragma unroll
    for (int i = 0; i < 4; ++i) sacc[i] = (float4v){0.f, 0.f, 0.f, 0.f};
    __builtin_amdgcn_s_setprio(1);
#pragma unroll
    for (int ks = 0; ks < 4; ++ks) {
#pragma unroll
      for (int nt = 0; nt < 4; ++nt) {
        short8 kb = *(const short8*)(kg + ((ks * 4 + nt) << 9) + lofs);
        sacc[nt] = __builtin_amdgcn_mfma_f32_16x16x32_bf16(qf[ks], kb, sacc[nt], 0, 0, 0);
      }
    }
    __builtin_amdgcn_s_setprio(0);

    // ---- mask + row max ----
    const bool full = (k0 + 63 <= rb) && ((rb + 15 - k0) <= WIN - 1);
    float sv[4][4];
    float rmax[4] = {NEG_BIG, NEG_BIG, NEG_BIG, NEG_BIG};
    if (full) {
#pragma unroll
      for (int nt = 0; nt < 4; ++nt)
#pragma unroll
        for (int r = 0; r < 4; ++r) {
          const float sx = sacc[nt][r] * SM_SCALE;
          sv[nt][r] = sx;
          rmax[r] = fmaxf(rmax[r], sx);
        }
    } else {
#pragma unroll
      for (int nt = 0; nt < 4; ++nt) {
        const int j = k0 + nt * 16 + lc;
#pragma unroll
        for (int r = 0; r < 4; ++r) {
          const int i = rb + quad * 4 + r;
          const bool valid = (j <= i) && (i - j < WIN);
          const float sx = valid ? sacc[nt][r] * SM_SCALE : NEG_BIG;
          sv[nt][r] = sx;
          rmax[r] = fmaxf(rmax[r], sx);
        }
      }
    }
#pragma unroll
    for (int off = 1; off < 16; off <<= 1)
#pragma unroll
      for (int r = 0; r < 4; ++r)
        rmax[r] = fmaxf(rmax[r], __shfl_xor(rmax[r], off, 64));

    // defer-rescale: only rescale when some row max actually grew
    bool grow = false;
#pragma unroll
    for (int r = 0; r < 4; ++r) grow |= (rmax[r] > mrow[r]);
    if (__any((int)grow)) {
#pragma unroll
      for (int r = 0; r < 4; ++r) {
        const float mn = fmaxf(mrow[r], rmax[r]);
        const float a  = __expf(mrow[r] - mn);
        mrow[r] = mn;
        lrow[r] *= a;
#pragma unroll
        for (int i = 0; i < 8; ++i) o[i][r] *= a;
      }
    }

    // ---- exp + P store (same-wave LDS, no barrier) + row sum ----
    float rsum[4] = {0.f, 0.f, 0.f, 0.f};
#pragma unroll
    for (int nt = 0; nt < 4; ++nt)
#pragma unroll
      for (int r = 0; r < 4; ++r) {
        const float p = __expf(sv[nt][r] - mrow[r]);   // masked: exp(-1e30-m)=0
        rsum[r] += p;
        P[(quad * 4 + r) * 72 + nt * 16 + lc] = f2bf(p);
      }
#pragma unroll
    for (int off = 1; off < 16; off <<= 1)
#pragma unroll
      for (int r = 0; r < 4; ++r)
        rsum[r] += __shfl_xor(rsum[r], off, 64);
#pragma unroll
    for (int r = 0; r < 4; ++r) lrow[r] += rsum[r];

    // ---- PV: P from LDS, V^T fragments straight from L2, coalesced ----
    __builtin_amdgcn_s_setprio(1);
#pragma unroll
    for (int ktk = 0; ktk < 2; ++ktk) {
      short8 pa = *(const short8*)(P + lc * 72 + ktk * 32 + quad * 8);
#pragma unroll
      for (int nt2 = 0; nt2 < 8; ++nt2) {
        short8 vb = *(const short8*)(vg + ((ktk * 8 + nt2) << 9) + lofs);
        o[nt2] = __builtin_amdgcn_mfma_f32_16x16x32_bf16(pa, vb, o[nt2], 0, 0, 0);
      }
    }
    __builtin_amdgcn_s_setprio(0);
  }

  // epilogue: normalized O -> packed-A ATTN layout [mblk][kstep][kc][m][8]
#pragma unroll
  for (int r = 0; r < 4; ++r) {
    const float inv = (lrow[r] > 0.f) ? (1.f / lrow[r]) : 0.f;
    const int row = rb + quad * 4 + r;
    const size_t mbase = (size_t)(row >> 7) * 64;
    const int m = row & 127;
#pragma unroll
    for (int nt2 = 0; nt2 < 8; ++nt2) {
      const int col = h * HD + nt2 * 16 + lc;
      const int kstep = col >> 5, kc = (col >> 3) & 3, e = col & 7;
      out[(mbase + kstep) * 4096 + kc * 1024 + m * 8 + e] = f2bf(o[nt2][r] * inv);
    }
  }
}

// ---------------------------------------------------------------------------
extern "C" void kernel_launch(void* const* d_in, const int* in_sizes, int n_in,
                              void* d_out, int out_size, void* d_ws, size_t ws_size,
                              hipStream_t stream) {
  const float* hs = (const float*)d_in[0];   // fp32
  const float* fc = (const float*)d_in[1];   // fp32
  // d_in[2] attention_mask all-true; d_in[3] causal analytic; d_in[4] arange
  const float* Wq = (const float*)d_in[5];
  const float* Wk = (const float*)d_in[6];
  const float* Wv = (const float*)d_in[7];
  const float* Wo = (const float*)d_in[8];
  float* outp = (float*)d_out;               // fp32 output

  u16* hsB   = (u16*)d_ws;                           // packed A, 2048x2048
  u16* WqkvT = hsB   + (size_t)2048 * 2048;          // packed B, 3072x2048
  u16* WoT   = WqkvT + (size_t)3072 * 2048;          // packed B, 2048x2048
  u16* Qb    = WoT   + (size_t)2048 * 2048;          // row-major 2048x2048
  u16* ATTN  = Qb    + (size_t)2048 * 2048;          // packed A, 2048x2048
  u16* Kp    = ATTN  + (size_t)2048 * 2048;          // 4 x 32 x 64 x 128 (frag order)
  u16* Vp    = Kp    + (size_t)4 * 2048 * 128;       // 4 x 32 x 128 x 64 (frag order)

  dim3 blk(256);
  prep<<<dim3(11264), blk, 0, stream>>>(hs, Wq, Wk, Wv, Wo, hsB, WqkvT, WoT);
  gemm_bt<1><<<dim3(3072 / 64, 2048 / 128), blk, 0, stream>>>(
      hsB, WqkvT, nullptr, fc, Qb, Kp, Vp, 2048, 3072, 2048);
  attn_kernel<<<dim3(2048), dim3(64), 0, stream>>>(Qb, Kp, Vp, ATTN);
  gemm_bt<0><<<dim3(2048 / 64, 2048 / 128), blk, 0, stream>>>(
      ATTN, WoT, outp, nullptr, nullptr, nullptr, nullptr, 2048, 2048, 2048);
}

// Round 5
// 224.859 us; speedup vs baseline: 1.1260x; 1.1260x over previous
//
#include <hip/hip_runtime.h>
#include <hip/hip_bf16.h>
#include <stdint.h>

#define S_LEN 2048
#define HDIM  2048
#define NHQ   16
#define NKVH  4
#define HD    128
#define WIN   1024
#define SM_SCALE 0.08838834764831845f
#define NEG_BIG  -1.0e30f

typedef __attribute__((ext_vector_type(8))) short short8;
typedef __attribute__((ext_vector_type(4))) float float4v;
typedef unsigned short u16;

static __device__ __forceinline__ float bf2f(u16 u) {
  union { unsigned int i; float f; } v; v.i = ((unsigned int)u) << 16; return v.f;
}
static __device__ __forceinline__ u16 f2bf(float f) {
  union { float f; unsigned int i; } v; v.f = f;
  unsigned int x = v.i;
  return (u16)((x + 0x7fffu + ((x >> 16) & 1u)) >> 16);   // RNE, finite inputs
}

// ---------------------------------------------------------------------------
// prep: one kernel for all input conditioning.
//  blocks [0,1024):        hs fp32 -> packed-A bf16 (8KB tiles [kc][m 128][8])
//  blocks [1024,7168):     Wq|Wk|Wv -> packed-B WqkvT (4KB tiles [kc][n 64][8])
//  blocks [7168,11264):    Wo -> packed-B WoT
// ---------------------------------------------------------------------------
__global__ __launch_bounds__(256) void prep(
    const float* __restrict__ hs, const float* __restrict__ Wq,
    const float* __restrict__ Wk, const float* __restrict__ Wv,
    const float* __restrict__ Wo, u16* __restrict__ hsB,
    u16* __restrict__ WqkvT, u16* __restrict__ WoT)
{
  const int b = blockIdx.x;
  if (b < 1024) {
    // ---- hs pack ----
    u16* dst = hsB + (size_t)b * 4096;
    const int mb = b >> 6, ks = b & 63;
#pragma unroll
    for (int i = 0; i < 2; ++i) {
      const int cid = i * 256 + threadIdx.x;
      const int kc  = cid & 3;
      const int m   = cid >> 2;
      const float* src = hs + ((size_t)(mb * 128 + m)) * 2048 + ks * 32 + kc * 8;
      const float4 v0 = *(const float4*)src;
      const float4 v1 = *(const float4*)(src + 4);
      short8 o;
      o[0] = (short)f2bf(v0.x); o[1] = (short)f2bf(v0.y);
      o[2] = (short)f2bf(v0.z); o[3] = (short)f2bf(v0.w);
      o[4] = (short)f2bf(v1.x); o[5] = (short)f2bf(v1.y);
      o[6] = (short)f2bf(v1.z); o[7] = (short)f2bf(v1.w);
      *(short8*)(dst + (kc * 128 + m) * 8) = o;
    }
    return;
  }

  // ---- weight transpose -> packed B ----
  __shared__ u16 t[32][33];
  const int tx = threadIdx.x & 31, ty = threadIdx.x >> 5;
  int n0, kstep;
  const float* W; u16* DT; int nsrc, N;
  if (b < 7168) {
    const int bb = b - 1024;            // 96 n-tiles x 64 k-tiles
    n0    = (bb % 96) * 32;
    kstep = bb / 96;
    if (n0 < 2048)      { W = Wq; nsrc = n0;        N = 2048; }
    else if (n0 < 2560) { W = Wk; nsrc = n0 - 2048; N = 512;  }
    else                { W = Wv; nsrc = n0 - 2560; N = 512;  }
    DT = WqkvT;
  } else {
    const int bb = b - 7168;            // 64 x 64
    n0    = (bb & 63) * 32;
    kstep = bb >> 6;
    W = Wo; nsrc = n0; N = 2048; DT = WoT;
  }
  const int k0 = kstep * 32;

#pragma unroll
  for (int i = 0; i < 4; ++i)
    t[ty + i * 8][tx] = f2bf(W[(size_t)(k0 + ty + i * 8) * N + nsrc + tx]);
  __syncthreads();
  const int kc = tx >> 3, e = tx & 7;
#pragma unroll
  for (int i = 0; i < 4; ++i) {
    const int n = n0 + ty + i * 8;
    DT[((size_t)((n >> 6) * 64 + kstep)) * 2048 + kc * 512 + (n & 63) * 8 + e]
        = t[tx][ty + i * 8];
  }
}

// ---------------------------------------------------------------------------
// GEMM on packed operands: C = A*B^T, bf16 in, fp32 accum. 128x64 tile,
// 4 waves of 64x32, conflict-free k-major LDS. Double-buffered staging
// (BK=64), stage(t+1) issued before compute(t), one barrier per K-step.
// EPI=0: fp32 row-major out (out-projection, writes d_out).
// EPI=1: fused QKV epilogue — in-register RoPE (q,k), route q->Qb, k->Kp, v->Vp.
//        Kp/Vp are stored in MFMA-FRAGMENT ORDER so the attention kernel's
//        direct-L2 reads are fully coalesced (1KB contiguous per instruction):
//        Kp tile: panel (ks 4, nt 4) x [lane 64][e 8]; value K[key][d] at
//                 panel=ks*4+(key>>4), lane=((d>>3)&3)*16+(key&15), e=d&7
//        Vp tile: panel (ktk 2, nt2 8) x [lane 64][e 8]; value V[key][hd] at
//                 panel=ktk*8+(hd>>4),  lane=((key>>3)&3)*16+(hd&15), e=key&7
// ---------------------------------------------------------------------------
template <int EPI>
__global__ __launch_bounds__(256) void gemm_bt(
    const u16* __restrict__ Apk, const u16* __restrict__ Bpk,
    void* __restrict__ Cv, const float* __restrict__ fc,
    u16* __restrict__ Qb, u16* __restrict__ Kp, u16* __restrict__ Vp,
    int M, int N, int K)
{
  __shared__ u16 Als[2][8192];   // 32 KB
  __shared__ u16 Bls[2][4096];   // 16 KB

  const int tid  = threadIdx.x;
  const int lane = tid & 63;
  const int w    = tid >> 6;
  const int quad = lane >> 4;
  const int lc   = lane & 15;
  const int n0   = blockIdx.x * 64;
  const int m0   = blockIdx.y * 128;
  const int wr   = (w >> 1) * 64;
  const int wc   = (w & 1) * 32;
  const int ktiles = K >> 5;        // packed 32-k tiles
  const int nk2    = ktiles >> 1;   // 64-k double steps

  const char* aB = (const char*)(Apk + (size_t)(m0 >> 7) * ktiles * 4096);
  const char* bB = (const char*)(Bpk + (size_t)(n0 >> 6) * ktiles * 2048);

  float4v acc[4][2];
#pragma unroll
  for (int i = 0; i < 4; ++i)
#pragma unroll
    for (int j = 0; j < 2; ++j) acc[i][j] = (float4v){0.f, 0.f, 0.f, 0.f};

  auto stage = [&](int bi, int kk) {
    const char* ab = aB + (size_t)kk * 16384;
    const char* bb = bB + (size_t)kk * 8192;
#pragma unroll
    for (int r = 0; r < 4; ++r) {
      const int off = r * 4096 + tid * 16;
      __builtin_amdgcn_global_load_lds(
          (__attribute__((address_space(1))) void*)(ab + off),
          (__attribute__((address_space(3))) void*)((char*)Als[bi] + off), 16, 0, 0);
    }
#pragma unroll
    for (int r = 0; r < 2; ++r) {
      const int off = r * 4096 + tid * 16;
      __builtin_amdgcn_global_load_lds(
          (__attribute__((address_space(1))) void*)(bb + off),
          (__attribute__((address_space(3))) void*)((char*)Bls[bi] + off), 16, 0, 0);
    }
  };

  stage(0, 0);
  __syncthreads();                 // drains vmcnt: buf0 ready
  int cur = 0;
  for (int kk = 0; kk < nk2; ++kk) {
    if (kk + 1 < nk2) stage(cur ^ 1, kk + 1);   // in flight across compute
#pragma unroll
    for (int half = 0; half < 2; ++half) {
      const u16* Ab = Als[cur] + half * 4096;
      const u16* Bb = Bls[cur] + half * 2048;
      short8 af[4], bfr[2];
#pragma unroll
      for (int mi = 0; mi < 4; ++mi)
        af[mi] = *(const short8*)(Ab + quad * 1024 + (wr + mi * 16 + lc) * 8);
#pragma unroll
      for (int ni = 0; ni < 2; ++ni)
        bfr[ni] = *(const short8*)(Bb + quad * 512 + (wc + ni * 16 + lc) * 8);
#pragma unroll
      for (int mi = 0; mi < 4; ++mi)
#pragma unroll
        for (int ni = 0; ni < 2; ++ni)
          acc[mi][ni] = __builtin_amdgcn_mfma_f32_16x16x32_bf16(
              af[mi], bfr[ni], acc[mi][ni], 0, 0, 0);
    }
    __syncthreads();               // next buf ready + cur free for restage
    cur ^= 1;
  }

  if (EPI == 0) {
#pragma unroll
    for (int mi = 0; mi < 4; ++mi)
#pragma unroll
      for (int ni = 0; ni < 2; ++ni)
#pragma unroll
        for (int r = 0; r < 4; ++r) {
          const int row = m0 + wr + mi * 16 + quad * 4 + r;
          const int col = n0 + wc + ni * 16 + lc;
          ((float*)Cv)[(size_t)row * N + col] = acc[mi][ni][r];
        }
  } else {
    // ---- fused QKV epilogue: rope (q,k) + pack routing (block-uniform) ----
    if (n0 < 2560) {
#pragma unroll
      for (int mi = 0; mi < 4; ++mi)
#pragma unroll
        for (int ni = 0; ni < 2; ++ni)
#pragma unroll
          for (int r = 0; r < 4; ++r) {
            const int row = m0 + wr + mi * 16 + quad * 4 + r;
            const int col = n0 + wc + ni * 16 + lc;
            const int hh  = col & 127;                 // dim within head
            const float v = acc[mi][ni][r];
            const float p = __shfl_xor(v, 1);
            const float2 cs = *(const float2*)(fc + row * 128 + (hh & ~1));
            const float res = (col & 1) ? (p * cs.y + v * cs.x)
                                        : (v * cs.x - p * cs.y);
            if (n0 < 2048) {
              Qb[(size_t)row * 2048 + col] = f2bf(res);
            } else {
              // K -> fragment-order pack
              const int kvh = (col - 2048) >> 7;
              const int kt  = row >> 6, key = row & 63;
              const int ks   = hh >> 5;
              const int qd   = (hh >> 3) & 3;
              const int e    = hh & 7;
              const int ntk  = key >> 4;
              const int lck  = key & 15;
              Kp[((size_t)(kvh * 32 + kt)) * 8192
                 + ((ks * 4 + ntk) << 9) + ((qd * 16 + lck) << 3) + e] = f2bf(res);
            }
          }
    } else {
      // v section: fragment-order pack (V^T fragments)
#pragma unroll
      for (int mi = 0; mi < 4; ++mi)
#pragma unroll
        for (int ni = 0; ni < 2; ++ni)
#pragma unroll
          for (int r = 0; r < 4; ++r) {
            const int row = m0 + wr + mi * 16 + quad * 4 + r;
            const int col = n0 + wc + ni * 16 + lc;
            const int kvh = (col - 2560) >> 7;
            const int hd  = col & 127;
            const int kt  = row >> 6, key = row & 63;
            const int ktk  = (key >> 5) & 1;
            const int qd   = (key >> 3) & 3;
            const int e    = key & 7;
            const int nt2  = hd >> 4;
            const int lcv  = hd & 15;
            Vp[((size_t)(kvh * 32 + kt)) * 8192
               + ((ktk * 8 + nt2) << 9) + ((qd * 16 + lcv) << 3) + e]
                = f2bf(acc[mi][ni][r]);
          }
    }
  }
}

// ---------------------------------------------------------------------------
// Flash attention v7 — register-pipelined 1-wave blocks:
//  * 2048 blocks x 64 threads: (t 32, h 16, w 4). ZERO barriers.
//  * Fragment-order Kp/Vp (r4 layout): every fragment load is one contiguous
//    coalesced 1KB transaction at base + panel*1KB + lane*16B.
//  * THE FIX vs v5/v6: v6 had VGPR_Count=64, so the 32 L2 loads per tile ran
//    load->wait->MFMA SERIALLY (~360cy x 32 = 11.7k cy/tile — the measured
//    floor of every previous round). Now: __launch_bounds__(64,2) (<=256
//    VGPRs) + software pipeline with loads issued a phase ahead:
//      prologue: issue 16 K loads (tile 0)
//      per tile: issue 16 V loads (this tile) -> QK (K regs resident)
//                -> issue 16 K loads (next tile) -> softmax (V landing)
//                -> PV
//    Per-register scoreboarding gives counted vmcnt waits; loads overlap the
//    ~800cy compute phase -> L2 latency fully hidden.
//  * sacc scaled/masked IN PLACE (saves 16 VGPRs).
// ---------------------------------------------------------------------------
__global__ __launch_bounds__(64, 2) void attn_kernel(
    const u16* __restrict__ Qb, const u16* __restrict__ kp,
    const u16* __restrict__ vp, u16* __restrict__ out)
{
  __shared__ u16 P[16 * 72];       // per-wave P tile, 2.25 KB

  const int lane = threadIdx.x;    // 0..63
  const int quad = lane >> 4;
  const int lc   = lane & 15;

  const int id = blockIdx.x;
  const int u  = id & 255;
  const int g  = id >> 8;          // 0..7
  const int h  = u & 15;
  const int w  = (u >> 4) & 3;
  const int j2 = u >> 6;           // 0..3
  const int t  = g * 4 + j2;       // 0..31 (bijective over (g,j2))
  const int kvh = h >> 2;
  const int rb  = t * 64 + w * 16; // first q-row of this wave

  short8 qf[4];
  {
    const u16* qp = Qb + (size_t)(rb + lc) * 2048 + h * HD + quad * 8;
#pragma unroll
    for (int ks = 0; ks < 4; ++ks) qf[ks] = *(const short8*)(qp + ks * 32);
  }

  float4v o[8];
#pragma unroll
  for (int i = 0; i < 8; ++i) o[i] = (float4v){0.f, 0.f, 0.f, 0.f};
  float mrow[4], lrow[4];
#pragma unroll
  for (int r = 0; r < 4; ++r) { mrow[r] = NEG_BIG; lrow[r] = 0.f; }

  int jmin = rb - (WIN - 1); if (jmin < 0) jmin = 0;
  const int kt_begin = jmin >> 6;
  const int kt_end   = (rb + 15) >> 6;

  const size_t tbase = (size_t)(kvh * 32) * 8192;
  const int lofs = lane << 3;      // lane*8 elements = lane*16B

  // ---- prologue: K fragments for the first tile, all 16 in flight ----
  short8 ka[8], kb8[8];
  {
    const u16* kg = kp + tbase + (size_t)kt_begin * 8192;
#pragma unroll
    for (int i = 0; i < 8; ++i) ka[i]  = *(const short8*)(kg + (i << 9) + lofs);
#pragma unroll
    for (int i = 0; i < 8; ++i) kb8[i] = *(const short8*)(kg + ((8 + i) << 9) + lofs);
  }

  for (int kt = kt_begin; kt <= kt_end; ++kt) {
    const int k0 = kt * 64;

    // ---- issue V loads for THIS tile (consumed after softmax) ----
    short8 va[8], vb8[8];
    {
      const u16* vg = vp + tbase + (size_t)kt * 8192;
#pragma unroll
      for (int i = 0; i < 8; ++i) va[i]  = *(const short8*)(vg + (i << 9) + lofs);
#pragma unroll
      for (int i = 0; i < 8; ++i) vb8[i] = *(const short8*)(vg + ((8 + i) << 9) + lofs);
    }

    // ---- QK^T: K fragments already resident ----
    float4v sacc[4];
#pragma unroll
    for (int i = 0; i < 4; ++i) sacc[i] = (float4v){0.f, 0.f, 0.f, 0.f};
    __builtin_amdgcn_s_setprio(1);
#pragma unroll
    for (int nt = 0; nt < 4; ++nt) {
      sacc[nt] = __builtin_amdgcn_mfma_f32_16x16x32_bf16(qf[0], ka[nt],      sacc[nt], 0, 0, 0);
      sacc[nt] = __builtin_amdgcn_mfma_f32_16x16x32_bf16(qf[1], ka[4 + nt],  sacc[nt], 0, 0, 0);
      sacc[nt] = __builtin_amdgcn_mfma_f32_16x16x32_bf16(qf[2], kb8[nt],     sacc[nt], 0, 0, 0);
      sacc[nt] = __builtin_amdgcn_mfma_f32_16x16x32_bf16(qf[3], kb8[4 + nt], sacc[nt], 0, 0, 0);
    }
    __builtin_amdgcn_s_setprio(0);

    // ---- prefetch K fragments for the NEXT tile (K regs now dead) ----
    if (kt < kt_end) {
      const u16* kg = kp + tbase + (size_t)(kt + 1) * 8192;
#pragma unroll
      for (int i = 0; i < 8; ++i) ka[i]  = *(const short8*)(kg + (i << 9) + lofs);
#pragma unroll
      for (int i = 0; i < 8; ++i) kb8[i] = *(const short8*)(kg + ((8 + i) << 9) + lofs);
    }

    // ---- mask + scale IN PLACE + row max ----
    const bool full = (k0 + 63 <= rb) && ((rb + 15 - k0) <= WIN - 1);
    float rmax[4] = {NEG_BIG, NEG_BIG, NEG_BIG, NEG_BIG};
    if (full) {
#pragma unroll
      for (int nt = 0; nt < 4; ++nt)
#pragma unroll
        for (int r = 0; r < 4; ++r) {
          const float sx = sacc[nt][r] * SM_SCALE;
          sacc[nt][r] = sx;
          rmax[r] = fmaxf(rmax[r], sx);
        }
    } else {
#pragma unroll
      for (int nt = 0; nt < 4; ++nt) {
        const int j = k0 + nt * 16 + lc;
#pragma unroll
        for (int r = 0; r < 4; ++r) {
          const int i = rb + quad * 4 + r;
          const bool valid = (j <= i) && (i - j < WIN);
          const float sx = valid ? sacc[nt][r] * SM_SCALE : NEG_BIG;
          sacc[nt][r] = sx;
          rmax[r] = fmaxf(rmax[r], sx);
        }
      }
    }
#pragma unroll
    for (int off = 1; off < 16; off <<= 1)
#pragma unroll
      for (int r = 0; r < 4; ++r)
        rmax[r] = fmaxf(rmax[r], __shfl_xor(rmax[r], off, 64));

    // defer-rescale: only rescale when some row max actually grew
    bool grow = false;
#pragma unroll
    for (int r = 0; r < 4; ++r) grow |= (rmax[r] > mrow[r]);
    if (__any((int)grow)) {
#pragma unroll
      for (int r = 0; r < 4; ++r) {
        const float mn = fmaxf(mrow[r], rmax[r]);
        const float a  = __expf(mrow[r] - mn);
        mrow[r] = mn;
        lrow[r] *= a;
#pragma unroll
        for (int i = 0; i < 8; ++i) o[i][r] *= a;
      }
    }

    // ---- exp + P store (same-wave LDS, no barrier) + row sum ----
    float rsum[4] = {0.f, 0.f, 0.f, 0.f};
#pragma unroll
    for (int nt = 0; nt < 4; ++nt)
#pragma unroll
      for (int r = 0; r < 4; ++r) {
        const float p = __expf(sacc[nt][r] - mrow[r]);   // masked: exp(-1e30-m)=0
        rsum[r] += p;
        P[(quad * 4 + r) * 72 + nt * 16 + lc] = f2bf(p);
      }
#pragma unroll
    for (int off = 1; off < 16; off <<= 1)
#pragma unroll
      for (int r = 0; r < 4; ++r)
        rsum[r] += __shfl_xor(rsum[r], off, 64);
#pragma unroll
    for (int r = 0; r < 4; ++r) lrow[r] += rsum[r];

    // ---- PV: P from LDS, V fragments landed during softmax ----
    __builtin_amdgcn_s_setprio(1);
    {
      short8 pa0 = *(const short8*)(P + lc * 72 + quad * 8);
#pragma unroll
      for (int nt2 = 0; nt2 < 8; ++nt2)
        o[nt2] = __builtin_amdgcn_mfma_f32_16x16x32_bf16(pa0, va[nt2], o[nt2], 0, 0, 0);
      short8 pa1 = *(const short8*)(P + lc * 72 + 32 + quad * 8);
#pragma unroll
      for (int nt2 = 0; nt2 < 8; ++nt2)
        o[nt2] = __builtin_amdgcn_mfma_f32_16x16x32_bf16(pa1, vb8[nt2], o[nt2], 0, 0, 0);
    }
    __builtin_amdgcn_s_setprio(0);
  }

  // epilogue: normalized O -> packed-A ATTN layout [mblk][kstep][kc][m][8]
#pragma unroll
  for (int r = 0; r < 4; ++r) {
    const float inv = (lrow[r] > 0.f) ? (1.f / lrow[r]) : 0.f;
    const int row = rb + quad * 4 + r;
    const size_t mbase = (size_t)(row >> 7) * 64;
    const int m = row & 127;
#pragma unroll
    for (int nt2 = 0; nt2 < 8; ++nt2) {
      const int col = h * HD + nt2 * 16 + lc;
      const int kstep = col >> 5, kc = (col >> 3) & 3, e = col & 7;
      out[(mbase + kstep) * 4096 + kc * 1024 + m * 8 + e] = f2bf(o[nt2][r] * inv);
    }
  }
}

// ---------------------------------------------------------------------------
extern "C" void kernel_launch(void* const* d_in, const int* in_sizes, int n_in,
                              void* d_out, int out_size, void* d_ws, size_t ws_size,
                              hipStream_t stream) {
  const float* hs = (const float*)d_in[0];   // fp32
  const float* fc = (const float*)d_in[1];   // fp32
  // d_in[2] attention_mask all-true; d_in[3] causal analytic; d_in[4] arange
  const float* Wq = (const float*)d_in[5];
  const float* Wk = (const float*)d_in[6];
  const float* Wv = (const float*)d_in[7];
  const float* Wo = (const float*)d_in[8];
  float* outp = (float*)d_out;               // fp32 output

  u16* hsB   = (u16*)d_ws;                           // packed A, 2048x2048
  u16* WqkvT = hsB   + (size_t)2048 * 2048;          // packed B, 3072x2048
  u16* WoT   = WqkvT + (size_t)3072 * 2048;          // packed B, 2048x2048
  u16* Qb    = WoT   + (size_t)2048 * 2048;          // row-major 2048x2048
  u16* ATTN  = Qb    + (size_t)2048 * 2048;          // packed A, 2048x2048
  u16* Kp    = ATTN  + (size_t)2048 * 2048;          // 4 x 32 x 64 x 128 (frag order)
  u16* Vp    = Kp    + (size_t)4 * 2048 * 128;       // 4 x 32 x 128 x 64 (frag order)

  dim3 blk(256);
  prep<<<dim3(11264), blk, 0, stream>>>(hs, Wq, Wk, Wv, Wo, hsB, WqkvT, WoT);
  gemm_bt<1><<<dim3(3072 / 64, 2048 / 128), blk, 0, stream>>>(
      hsB, WqkvT, nullptr, fc, Qb, Kp, Vp, 2048, 3072, 2048);
  attn_kernel<<<dim3(2048), dim3(64), 0, stream>>>(Qb, Kp, Vp, ATTN);
  gemm_bt<0><<<dim3(2048 / 64, 2048 / 128), blk, 0, stream>>>(
      ATTN, WoT, outp, nullptr, nullptr, nullptr, nullptr, 2048, 2048, 2048);
}